// Round 1
// baseline (3332.858 us; speedup 1.0000x reference)
//
#include <hip/hip_runtime.h>
#include <hip/hip_bf16.h>
#include <cstddef>

#define BATCH 8
#define SEQ   2048
#define DEMB  1024
#define DQ    512

// ---------------------------------------------------------------------------
// Projection GEMM (fp32): C[M,N] = X[M,K] * W[K,N]; M=16384, K=1024, N=512.
// BM=64, BN=64, BK=32, 256 threads, 4x4 register tile per thread.
// blockIdx.z selects (Wq->Q, Wk->K, Wv->V).
// ---------------------------------------------------------------------------
__global__ __launch_bounds__(256) void proj_gemm(
    const float* __restrict__ x,
    const float* __restrict__ Wq, const float* __restrict__ Wk,
    const float* __restrict__ Wv,
    float* __restrict__ Qo, float* __restrict__ Ko, float* __restrict__ Vo)
{
  const float* W; float* O;
  if (blockIdx.z == 0)      { W = Wq; O = Qo; }
  else if (blockIdx.z == 1) { W = Wk; O = Ko; }
  else                      { W = Wv; O = Vo; }

  __shared__ float At[32][68];   // [k][m], padded
  __shared__ float Bs[32][68];   // [k][n], padded

  const int tid = threadIdx.x;
  const int ty = tid >> 4;       // 0..15 -> m sub-tile
  const int tx = tid & 15;       // 0..15 -> n sub-tile
  const int m0 = blockIdx.y * 64;
  const int n0 = blockIdx.x * 64;

  float acc[4][4] = {};

  for (int k0 = 0; k0 < DEMB; k0 += 32) {
    // stage A tile (64 rows x 32 k) transposed into At[k][m]
    #pragma unroll
    for (int i = 0; i < 2; i++) {
      int row = (tid >> 3) + i * 32;       // 0..63
      int kq  = tid & 7;                   // float4 index in k
      float4 a = *(const float4*)&x[(size_t)(m0 + row) * DEMB + k0 + kq * 4];
      At[kq*4+0][row] = a.x; At[kq*4+1][row] = a.y;
      At[kq*4+2][row] = a.z; At[kq*4+3][row] = a.w;
    }
    // stage B tile (32 k x 64 n) naturally
    #pragma unroll
    for (int i = 0; i < 2; i++) {
      int kr = (tid >> 4) + i * 16;        // 0..31
      int nq = tid & 15;
      *(float4*)&Bs[kr][nq*4] =
          *(const float4*)&W[(size_t)(k0 + kr) * DQ + n0 + nq * 4];
    }
    __syncthreads();
    #pragma unroll 8
    for (int k = 0; k < 32; k++) {
      float4 av = *(const float4*)&At[k][ty*4];
      float4 bv = *(const float4*)&Bs[k][tx*4];
      float a[4] = {av.x, av.y, av.z, av.w};
      float b[4] = {bv.x, bv.y, bv.z, bv.w};
      #pragma unroll
      for (int i = 0; i < 4; i++)
        #pragma unroll
        for (int j = 0; j < 4; j++) acc[i][j] += a[i] * b[j];
    }
    __syncthreads();
  }

  #pragma unroll
  for (int i = 0; i < 4; i++) {
    float4 o = make_float4(acc[i][0], acc[i][1], acc[i][2], acc[i][3]);
    *(float4*)&O[(size_t)(m0 + ty*4 + i) * DQ + n0 + tx * 4] = o;
  }
}

// ---------------------------------------------------------------------------
// Flash attention, fp32, no scaling, key-mask = exactly -1e9 when mask==0.
// 128 threads (2 waves); 32 query rows per block; key tiles of 64;
// D=512 chunked by 64. Q is read from the `out` buffer (written by proj_gemm)
// and overwritten with O only in the epilogue (each block owns its rows).
// ---------------------------------------------------------------------------
__global__ __launch_bounds__(128, 2) void flash_attn(
    const float* Qg,                     // aliases Out - no __restrict__
    const float* __restrict__ Kg,
    const float* __restrict__ Vg,
    const int*   __restrict__ maskg,
    float* Outg)                         // aliases Qg - no __restrict__
{
  const int b  = blockIdx.y;
  const int q0 = blockIdx.x * 32;
  const float* Qb = Qg + ((size_t)b * SEQ + q0) * DQ;
  const float* Kb = Kg + (size_t)b * SEQ * DQ;
  const float* Vb = Vg + (size_t)b * SEQ * DQ;
  const int*   mb = maskg + b * SEQ;
  float*       Ob = Outg + ((size_t)b * SEQ + q0) * DQ;

  __shared__ float Qt[64][36];   // [d][r] transposed Q chunk
  __shared__ float Kt[64][68];   // [d][s] transposed K chunk
  __shared__ float Vs[64][68];   // [s][d] V chunk
  __shared__ float Pt[64][36];   // [s][r] probabilities

  const int tid = threadIdx.x;
  const int ty = tid >> 4;       // 0..7  -> rows r0 = ty*4
  const int tx = tid & 15;       // 0..15 -> cols s0/c0 = tx*4

  float Oacc[8][4][4];
  #pragma unroll
  for (int ch = 0; ch < 8; ch++)
    #pragma unroll
    for (int i = 0; i < 4; i++)
      #pragma unroll
      for (int j = 0; j < 4; j++) Oacc[ch][i][j] = 0.f;

  float m_run[4], l_run[4];
  #pragma unroll
  for (int i = 0; i < 4; i++) { m_run[i] = -3.0e38f; l_run[i] = 0.f; }

  for (int kt = 0; kt < SEQ / 64; kt++) {
    const int s0g = kt * 64;

    // ---------------- Phase A: S = Q K^T over full D ----------------
    float S[4][4] = {};
    #pragma unroll 1
    for (int ch = 0; ch < 8; ch++) {
      // stage Qt: 32 rows x 64 d, transposed (512 float4, 4/thread)
      #pragma unroll
      for (int i = 0; i < 4; i++) {
        int idx = tid + i * 128;           // 0..511
        int row = idx >> 4;                // 0..31
        int dq  = idx & 15;
        float4 q4 = *(const float4*)&Qb[(size_t)row * DQ + ch * 64 + dq * 4];
        Qt[dq*4+0][row] = q4.x; Qt[dq*4+1][row] = q4.y;
        Qt[dq*4+2][row] = q4.z; Qt[dq*4+3][row] = q4.w;
      }
      // stage Kt: 64 rows x 64 d, transposed (1024 float4, 8/thread)
      #pragma unroll
      for (int i = 0; i < 8; i++) {
        int idx = tid + i * 128;           // 0..1023
        int srow = idx >> 4;               // 0..63
        int dq   = idx & 15;
        float4 k4 =
            *(const float4*)&Kb[(size_t)(s0g + srow) * DQ + ch * 64 + dq * 4];
        Kt[dq*4+0][srow] = k4.x; Kt[dq*4+1][srow] = k4.y;
        Kt[dq*4+2][srow] = k4.z; Kt[dq*4+3][srow] = k4.w;
      }
      __syncthreads();
      #pragma unroll 16
      for (int d = 0; d < 64; d++) {
        float4 qv = *(const float4*)&Qt[d][ty*4];
        float4 kv = *(const float4*)&Kt[d][tx*4];
        float qa[4] = {qv.x, qv.y, qv.z, qv.w};
        float ka[4] = {kv.x, kv.y, kv.z, kv.w};
        #pragma unroll
        for (int i = 0; i < 4; i++)
          #pragma unroll
          for (int j = 0; j < 4; j++) S[i][j] += qa[i] * ka[j];
      }
      __syncthreads();
    }

    // ---------------- mask + online softmax ----------------
    int msel[4];
    #pragma unroll
    for (int j = 0; j < 4; j++) msel[j] = mb[s0g + tx * 4 + j];

    #pragma unroll
    for (int i = 0; i < 4; i++) {
      float sv[4];
      #pragma unroll
      for (int j = 0; j < 4; j++) sv[j] = msel[j] ? S[i][j] : -1.0e9f;
      float tmax = fmaxf(fmaxf(sv[0], sv[1]), fmaxf(sv[2], sv[3]));
      #pragma unroll
      for (int off = 1; off < 16; off <<= 1)
        tmax = fmaxf(tmax, __shfl_xor(tmax, off, 64));
      float mnew  = fmaxf(m_run[i], tmax);
      float scale = __expf(m_run[i] - mnew);
      float p[4], ps = 0.f;
      #pragma unroll
      for (int j = 0; j < 4; j++) { p[j] = __expf(sv[j] - mnew); ps += p[j]; }
      #pragma unroll
      for (int off = 1; off < 16; off <<= 1) ps += __shfl_xor(ps, off, 64);
      l_run[i] = l_run[i] * scale + ps;
      m_run[i] = mnew;
      #pragma unroll
      for (int ch = 0; ch < 8; ch++)
        #pragma unroll
        for (int j = 0; j < 4; j++) Oacc[ch][i][j] *= scale;
      #pragma unroll
      for (int j = 0; j < 4; j++) Pt[tx*4+j][ty*4+i] = p[j];
    }
    // Pt visibility is covered by the barrier after the first Vs staging.

    // ---------------- Phase B: O += P V ----------------
    #pragma unroll
    for (int ch = 0; ch < 8; ch++) {
      #pragma unroll
      for (int i = 0; i < 8; i++) {
        int idx = tid + i * 128;
        int srow = idx >> 4;
        int dq   = idx & 15;
        *(float4*)&Vs[srow][dq*4] =
            *(const float4*)&Vb[(size_t)(s0g + srow) * DQ + ch * 64 + dq * 4];
      }
      __syncthreads();
      #pragma unroll 4
      for (int s = 0; s < 64; s++) {
        float4 pv = *(const float4*)&Pt[s][ty*4];
        float4 vv = *(const float4*)&Vs[s][tx*4];
        float pa[4] = {pv.x, pv.y, pv.z, pv.w};
        float va[4] = {vv.x, vv.y, vv.z, vv.w};
        #pragma unroll
        for (int i = 0; i < 4; i++)
          #pragma unroll
          for (int j = 0; j < 4; j++) Oacc[ch][i][j] += pa[i] * va[j];
      }
      __syncthreads();
    }
  }

  // ---------------- epilogue: normalize and store ----------------
  #pragma unroll
  for (int i = 0; i < 4; i++) {
    float inv = 1.0f / l_run[i];
    #pragma unroll
    for (int ch = 0; ch < 8; ch++) {
      float4 o = make_float4(Oacc[ch][i][0] * inv, Oacc[ch][i][1] * inv,
                             Oacc[ch][i][2] * inv, Oacc[ch][i][3] * inv);
      *(float4*)&Ob[(size_t)(ty*4 + i) * DQ + ch * 64 + tx * 4] = o;
    }
  }
}

extern "C" void kernel_launch(void* const* d_in, const int* in_sizes, int n_in,
                              void* d_out, int out_size, void* d_ws, size_t ws_size,
                              hipStream_t stream)
{
  const float* x    = (const float*)d_in[0];
  const float* Wq   = (const float*)d_in[1];
  const float* Wk   = (const float*)d_in[2];
  const float* Wv   = (const float*)d_in[3];
  const int*   mask = (const int*)d_in[4];
  float* out = (float*)d_out;

  float* Kbuf = (float*)d_ws;                      // 33.5 MB
  float* Vbuf = Kbuf + (size_t)BATCH * SEQ * DQ;   // 33.5 MB

  // Q -> d_out (flash_attn overwrites it with O row-for-row at the end)
  dim3 pgrid(DQ / 64, (BATCH * SEQ) / 64, 3);
  proj_gemm<<<pgrid, 256, 0, stream>>>(x, Wq, Wk, Wv, out, Kbuf, Vbuf);

  dim3 agrid(SEQ / 32, BATCH);
  flash_attn<<<agrid, 128, 0, stream>>>(out, Kbuf, Vbuf, mask, out);
}

// Round 2
// 837.118 us; speedup vs baseline: 3.9813x; 3.9813x over previous
//
#include <hip/hip_runtime.h>
#include <hip/hip_bf16.h>
#include <cstddef>

#define BATCH 8
#define SEQ   2048
#define DEMB  1024
#define DQ    512

typedef __attribute__((ext_vector_type(8))) short bf16x8;
typedef __attribute__((ext_vector_type(4))) float f32x4;
typedef __attribute__((ext_vector_type(4))) unsigned short u16x4;

static __device__ __forceinline__ unsigned short bft(float f) {
  union { float f; unsigned u; } v; v.f = f;
  return (unsigned short)(v.u >> 16);            // truncating fp32->bf16
}
static __device__ __forceinline__ float bf2f(unsigned short h) {
  union { float f; unsigned u; } v; v.u = ((unsigned)h) << 16;
  return v.f;
}

// ---------------------------------------------------------------------------
// Split the three weight matrices into (hi, lo) bf16 planes, TRANSPOSED to
// [n][k] layout so the GEMM B-fragment (8 consecutive k per lane) is a 16B load.
// ---------------------------------------------------------------------------
__global__ __launch_bounds__(256) void wsplit(
    const float* __restrict__ Wq, const float* __restrict__ Wk,
    const float* __restrict__ Wv,
    unsigned short* __restrict__ whi, unsigned short* __restrict__ wlo)
{
  int qidx = blockIdx.x * 256 + threadIdx.x;     // 0 .. 3*1024*128-1
  int w   = qidx >> 17;                          // / (1024*128)
  int rem = qidx & 131071;
  int k   = rem >> 7;                            // 0..1023
  int n   = (rem & 127) * 4;                     // 0..508
  const float* W = (w == 0) ? Wq : (w == 1) ? Wk : Wv;
  float4 v = *(const float4*)&W[(size_t)k * DQ + n];
  float vv[4] = {v.x, v.y, v.z, v.w};
  size_t base = (size_t)w * (DQ * DEMB);
  #pragma unroll
  for (int j = 0; j < 4; j++) {
    unsigned short h = bft(vv[j]);
    unsigned short lo = bft(vv[j] - bf2f(h));
    whi[base + (size_t)(n + j) * DEMB + k] = h;
    wlo[base + (size_t)(n + j) * DEMB + k] = lo;
  }
}

// ---------------------------------------------------------------------------
// Projection GEMM on MFMA, 2-term split, 3-pass (hi*hi + hi*lo + lo*hi).
// C[M=16384, N=512] = X[M,K=1024] * W[K,N].  BM=128, BN=128, BK=32,
// 256 threads = 4 waves of 64x64, 4x4 frags of 16x16x32.
// Outputs:
//   w=0 (Q): hi/lo planes packed block-local into d_out (32-row groups:
//            group g occupies halfs [g*32768, g*32768+32768): hi 32x512 then lo)
//   w=1 (K): khi/klo planes [b*2048+t][d]
//   w=2 (V): vt transposed [b][d][t] bf16 (single plane)
// ---------------------------------------------------------------------------
__global__ __launch_bounds__(256) void proj_mfma(
    const float* __restrict__ x,
    const unsigned short* __restrict__ whi,
    const unsigned short* __restrict__ wlo,
    unsigned short* __restrict__ khi, unsigned short* __restrict__ klo,
    unsigned short* __restrict__ vt,
    unsigned short* __restrict__ qpack)
{
  const int w  = blockIdx.z;
  const int mt = blockIdx.y, nt = blockIdx.x;

  __shared__ unsigned short Xh[128][40], Xl[128][40];  // [m][k], pad 40
  __shared__ unsigned short Wh[128][40], Wl[128][40];  // [n][k], pad 40

  const int tid  = threadIdx.x;
  const int wave = tid >> 6, l = tid & 63;
  const int wm = wave >> 1, wn = wave & 1;
  const int lo4 = l & 15, hi2 = l >> 4;

  f32x4 acc[4][4];
  #pragma unroll
  for (int mf = 0; mf < 4; mf++)
    #pragma unroll
    for (int nf = 0; nf < 4; nf++)
      #pragma unroll
      for (int i = 0; i < 4; i++) acc[mf][nf][i] = 0.f;

  const int    srow  = tid >> 1;
  const int    skh   = (tid & 1) * 16;
  const size_t xbase = (size_t)(mt * 128 + srow) * DEMB + skh;
  const size_t wbase = (size_t)w * (DQ * DEMB) + (size_t)(nt * 128 + srow) * DEMB + skh;

  #pragma unroll 1
  for (int k0 = 0; k0 < DEMB; k0 += 32) {
    // ---- stage X tile (fp32 -> hi/lo bf16 in-register) ----
    float xs[16];
    #pragma unroll
    for (int i = 0; i < 4; i++) {
      float4 t = *(const float4*)&x[xbase + k0 + i * 4];
      xs[i*4+0] = t.x; xs[i*4+1] = t.y; xs[i*4+2] = t.z; xs[i*4+3] = t.w;
    }
    #pragma unroll
    for (int i = 0; i < 4; i++) {
      u16x4 hv, lv;
      #pragma unroll
      for (int j = 0; j < 4; j++) {
        unsigned short h = bft(xs[i*4+j]);
        hv[j] = h;
        lv[j] = bft(xs[i*4+j] - bf2f(h));
      }
      *(u16x4*)&Xh[srow][skh + i*4] = hv;
      *(u16x4*)&Xl[srow][skh + i*4] = lv;
    }
    // ---- stage W tile (pre-split bf16 planes, already [n][k]) ----
    {
      bf16x8 a0 = *(const bf16x8*)&whi[wbase + k0];
      bf16x8 a1 = *(const bf16x8*)&whi[wbase + k0 + 8];
      bf16x8 b0 = *(const bf16x8*)&wlo[wbase + k0];
      bf16x8 b1 = *(const bf16x8*)&wlo[wbase + k0 + 8];
      *(bf16x8*)&Wh[srow][skh]     = a0;
      *(bf16x8*)&Wh[srow][skh + 8] = a1;
      *(bf16x8*)&Wl[srow][skh]     = b0;
      *(bf16x8*)&Wl[srow][skh + 8] = b1;
    }
    __syncthreads();

    bf16x8 ah[4], al[4], bh[4], bl[4];
    #pragma unroll
    for (int mf = 0; mf < 4; mf++) {
      ah[mf] = *(const bf16x8*)&Xh[wm*64 + mf*16 + lo4][hi2*8];
      al[mf] = *(const bf16x8*)&Xl[wm*64 + mf*16 + lo4][hi2*8];
    }
    #pragma unroll
    for (int nf = 0; nf < 4; nf++) {
      bh[nf] = *(const bf16x8*)&Wh[wn*64 + nf*16 + lo4][hi2*8];
      bl[nf] = *(const bf16x8*)&Wl[wn*64 + nf*16 + lo4][hi2*8];
    }
    #pragma unroll
    for (int mf = 0; mf < 4; mf++)
      #pragma unroll
      for (int nf = 0; nf < 4; nf++) {
        acc[mf][nf] = __builtin_amdgcn_mfma_f32_16x16x32_bf16(ah[mf], bh[nf], acc[mf][nf], 0, 0, 0);
        acc[mf][nf] = __builtin_amdgcn_mfma_f32_16x16x32_bf16(ah[mf], bl[nf], acc[mf][nf], 0, 0, 0);
        acc[mf][nf] = __builtin_amdgcn_mfma_f32_16x16x32_bf16(al[mf], bh[nf], acc[mf][nf], 0, 0, 0);
      }
    __syncthreads();
  }

  // ---- epilogue ----
  const int mb = mt * 128 + wm * 64;
  const int nb = nt * 128 + wn * 64;
  #pragma unroll
  for (int mf = 0; mf < 4; mf++)
    #pragma unroll
    for (int nf = 0; nf < 4; nf++)
      #pragma unroll
      for (int i = 0; i < 4; i++) {
        int m = mb + mf*16 + hi2*4 + i;
        int n = nb + nf*16 + lo4;
        float val = acc[mf][nf][i];
        if (w == 0) {
          unsigned short h  = bft(val);
          unsigned short lo = bft(val - bf2f(h));
          size_t base = (size_t)(m >> 5) * 32768 + (size_t)(m & 31) * 512 + n;
          qpack[base]         = h;
          qpack[base + 16384] = lo;
        } else if (w == 1) {
          unsigned short h  = bft(val);
          unsigned short lo = bft(val - bf2f(h));
          khi[(size_t)m * 512 + n] = h;
          klo[(size_t)m * 512 + n] = lo;
        } else {
          int bb = m >> 11, t = m & 2047;
          vt[(size_t)bb * (512 * 2048) + (size_t)n * 2048 + t] = bft(val);
        }
      }
}

// ---------------------------------------------------------------------------
// Flash attention on MFMA. 512 threads = 8 waves; 64 q-rows/block; 128-key
// tiles. Wave (qw,kw): qw=wave>>2 picks 32 q-rows, kw=wave&3 picks 32 keys
// (QK phase) / 128-d chunk (PV phase). QK^T is a 3-pass split; P exchanged
// through XOR-swizzled LDS; cross-wave online-softmax stats in LDS.
// Q is read from d_out (packed by proj) and overwritten with O at the end.
// ---------------------------------------------------------------------------
__global__ __launch_bounds__(512, 2) void flash_mfma(
    const unsigned short* __restrict__ khi,
    const unsigned short* __restrict__ klo,
    const unsigned short* __restrict__ vt,
    const int* __restrict__ maskg,
    float* dout)                          // aliases Q storage - no restrict
{
  const int b  = blockIdx.x & 7;          // batch pinned to XCD
  const int qt = blockIdx.x >> 3;
  const int q0 = qt * 64;

  const int tid  = threadIdx.x;
  const int wave = tid >> 6, l = tid & 63;
  const int qw = wave >> 2, kw = wave & 3;
  const int lo4 = l & 15, hi2 = l >> 4;

  __shared__ unsigned short P[64 * 128];  // 16KB, XOR-swizzled rows
  __shared__ float pmax[4][64], psum[4][64];

  const unsigned short* qpk = (const unsigned short*)dout
      + (size_t)(b * SEQ + q0) * 1024 + (size_t)qw * 32768 + (size_t)lo4 * 512;
  const unsigned short* kbh = khi + ((size_t)(b * SEQ) + kw * 32 + lo4) * 512;
  const unsigned short* kbl = klo + ((size_t)(b * SEQ) + kw * 32 + lo4) * 512;
  const unsigned short* vb  = vt + (size_t)b * (512 * 2048) + (size_t)(kw * 128 + lo4) * 2048;
  const int* mb = maskg + b * SEQ + kw * 32 + lo4;

  f32x4 o[2][8];
  #pragma unroll
  for (int qf = 0; qf < 2; qf++)
    #pragma unroll
    for (int dt = 0; dt < 8; dt++)
      #pragma unroll
      for (int i = 0; i < 4; i++) o[qf][dt][i] = 0.f;

  float m_run[2][4], l_run[2][4];
  #pragma unroll
  for (int qf = 0; qf < 2; qf++)
    #pragma unroll
    for (int i = 0; i < 4; i++) { m_run[qf][i] = -3.0e38f; l_run[qf][i] = 0.f; }

  #pragma unroll 1
  for (int kt = 0; kt < SEQ / 128; kt++) {
    const int key0 = kt * 128;

    // ---------------- QK^T (3-pass split), no LDS ----------------
    f32x4 S[2][2];
    #pragma unroll
    for (int qf = 0; qf < 2; qf++)
      #pragma unroll
      for (int kf = 0; kf < 2; kf++)
        #pragma unroll
        for (int i = 0; i < 4; i++) S[qf][kf][i] = 0.f;

    #pragma unroll 4
    for (int st = 0; st < 16; st++) {
      const int d0 = st * 32 + hi2 * 8;
      bf16x8 qh0 = *(const bf16x8*)(qpk + d0);
      bf16x8 qh1 = *(const bf16x8*)(qpk + 8192 + d0);
      bf16x8 ql0 = *(const bf16x8*)(qpk + 16384 + d0);
      bf16x8 ql1 = *(const bf16x8*)(qpk + 16384 + 8192 + d0);
      const size_t ko = (size_t)key0 * 512 + d0;
      bf16x8 kh0 = *(const bf16x8*)(kbh + ko);
      bf16x8 kh1 = *(const bf16x8*)(kbh + ko + 8192);
      bf16x8 kl0 = *(const bf16x8*)(kbl + ko);
      bf16x8 kl1 = *(const bf16x8*)(kbl + ko + 8192);
      S[0][0] = __builtin_amdgcn_mfma_f32_16x16x32_bf16(qh0, kh0, S[0][0], 0, 0, 0);
      S[0][1] = __builtin_amdgcn_mfma_f32_16x16x32_bf16(qh0, kh1, S[0][1], 0, 0, 0);
      S[1][0] = __builtin_amdgcn_mfma_f32_16x16x32_bf16(qh1, kh0, S[1][0], 0, 0, 0);
      S[1][1] = __builtin_amdgcn_mfma_f32_16x16x32_bf16(qh1, kh1, S[1][1], 0, 0, 0);
      S[0][0] = __builtin_amdgcn_mfma_f32_16x16x32_bf16(qh0, kl0, S[0][0], 0, 0, 0);
      S[0][1] = __builtin_amdgcn_mfma_f32_16x16x32_bf16(qh0, kl1, S[0][1], 0, 0, 0);
      S[1][0] = __builtin_amdgcn_mfma_f32_16x16x32_bf16(qh1, kl0, S[1][0], 0, 0, 0);
      S[1][1] = __builtin_amdgcn_mfma_f32_16x16x32_bf16(qh1, kl1, S[1][1], 0, 0, 0);
      S[0][0] = __builtin_amdgcn_mfma_f32_16x16x32_bf16(ql0, kh0, S[0][0], 0, 0, 0);
      S[0][1] = __builtin_amdgcn_mfma_f32_16x16x32_bf16(ql0, kh1, S[0][1], 0, 0, 0);
      S[1][0] = __builtin_amdgcn_mfma_f32_16x16x32_bf16(ql1, kh0, S[1][0], 0, 0, 0);
      S[1][1] = __builtin_amdgcn_mfma_f32_16x16x32_bf16(ql1, kh1, S[1][1], 0, 0, 0);
    }

    // ---------------- mask ----------------
    const int ms0 = mb[key0];
    const int ms1 = mb[key0 + 16];
    #pragma unroll
    for (int qf = 0; qf < 2; qf++)
      #pragma unroll
      for (int i = 0; i < 4; i++) {
        if (!ms0) S[qf][0][i] = -1.0e9f;
        if (!ms1) S[qf][1][i] = -1.0e9f;
      }

    // ---------------- online softmax (cross-wave) ----------------
    #pragma unroll
    for (int qf = 0; qf < 2; qf++)
      #pragma unroll
      for (int i = 0; i < 4; i++) {
        float mx = fmaxf(S[qf][0][i], S[qf][1][i]);
        #pragma unroll
        for (int off = 1; off < 16; off <<= 1)
          mx = fmaxf(mx, __shfl_xor(mx, off, 64));
        if (lo4 == 0) pmax[kw][qw*32 + qf*16 + hi2*4 + i] = mx;
      }
    __syncthreads();

    float mnew[2][4], scale[2][4];
    #pragma unroll
    for (int qf = 0; qf < 2; qf++)
      #pragma unroll
      for (int i = 0; i < 4; i++) {
        int row = qw*32 + qf*16 + hi2*4 + i;
        float pm = fmaxf(fmaxf(pmax[0][row], pmax[1][row]),
                         fmaxf(pmax[2][row], pmax[3][row]));
        float mn = fmaxf(m_run[qf][i], pm);
        mnew[qf][i]  = mn;
        scale[qf][i] = __expf(m_run[qf][i] - mn);
        m_run[qf][i] = mn;
      }
    #pragma unroll
    for (int qf = 0; qf < 2; qf++)
      #pragma unroll
      for (int dt = 0; dt < 8; dt++)
        #pragma unroll
        for (int i = 0; i < 4; i++) o[qf][dt][i] *= scale[qf][i];

    #pragma unroll
    for (int qf = 0; qf < 2; qf++)
      #pragma unroll
      for (int i = 0; i < 4; i++) {
        float p0 = __expf(S[qf][0][i] - mnew[qf][i]);
        float p1 = __expf(S[qf][1][i] - mnew[qf][i]);
        int row  = qw*32 + qf*16 + hi2*4 + i;
        int swz  = (row & 7) << 4;
        int b0   = (row*256 + (kw*32 + lo4)*2) ^ swz;
        int b1   = (row*256 + (kw*32 + 16 + lo4)*2) ^ swz;
        *(unsigned short*)((char*)P + b0) = bft(p0);
        *(unsigned short*)((char*)P + b1) = bft(p1);
        float ps = p0 + p1;
        #pragma unroll
        for (int off = 1; off < 16; off <<= 1) ps += __shfl_xor(ps, off, 64);
        if (lo4 == 0) psum[kw][row] = ps;
      }
    __syncthreads();

    #pragma unroll
    for (int qf = 0; qf < 2; qf++)
      #pragma unroll
      for (int i = 0; i < 4; i++) {
        int row = qw*32 + qf*16 + hi2*4 + i;
        float s = psum[0][row] + psum[1][row] + psum[2][row] + psum[3][row];
        l_run[qf][i] = l_run[qf][i] * scale[qf][i] + s;
      }

    // ---------------- PV: O += P * V ----------------
    #pragma unroll
    for (int ks = 0; ks < 4; ks++) {
      bf16x8 pa[2];
      #pragma unroll
      for (int qf = 0; qf < 2; qf++) {
        int row  = qw*32 + qf*16 + lo4;
        int byte = (row*256 + (ks*32 + hi2*8)*2) ^ ((row & 7) << 4);
        pa[qf] = *(const bf16x8*)((const char*)P + byte);
      }
      const unsigned short* vrow = vb + (size_t)(key0 + ks*32 + hi2*8);
      #pragma unroll
      for (int dt = 0; dt < 8; dt++) {
        bf16x8 vf = *(const bf16x8*)(vrow + (size_t)dt * 16 * 2048);
        o[0][dt] = __builtin_amdgcn_mfma_f32_16x16x32_bf16(pa[0], vf, o[0][dt], 0, 0, 0);
        o[1][dt] = __builtin_amdgcn_mfma_f32_16x16x32_bf16(pa[1], vf, o[1][dt], 0, 0, 0);
      }
    }
    __syncthreads();   // protect P/stats from next tile's writes
  }

  // ---------------- epilogue ----------------
  #pragma unroll
  for (int qf = 0; qf < 2; qf++)
    #pragma unroll
    for (int i = 0; i < 4; i++) {
      float inv  = 1.0f / l_run[qf][i];
      int   rowg = b * SEQ + q0 + qw*32 + qf*16 + hi2*4 + i;
      #pragma unroll
      for (int dt = 0; dt < 8; dt++)
        dout[(size_t)rowg * 512 + kw*128 + dt*16 + lo4] = o[qf][dt][i] * inv;
    }
}

extern "C" void kernel_launch(void* const* d_in, const int* in_sizes, int n_in,
                              void* d_out, int out_size, void* d_ws, size_t ws_size,
                              hipStream_t stream)
{
  const float* x    = (const float*)d_in[0];
  const float* Wq   = (const float*)d_in[1];
  const float* Wk   = (const float*)d_in[2];
  const float* Wv   = (const float*)d_in[3];
  const int*   mask = (const int*)d_in[4];

  unsigned short* wsh = (unsigned short*)d_ws;
  unsigned short* KHI = wsh;                 //  8,388,608 halfs
  unsigned short* KLO = wsh +  8388608;      //  8,388,608
  unsigned short* VT  = wsh + 16777216;      //  8,388,608
  unsigned short* WHI = wsh + 25165824;      //  1,572,864
  unsigned short* WLO = wsh + 26738688;      //  1,572,864  -> 56.6 MB total

  wsplit<<<1536, 256, 0, stream>>>(Wq, Wk, Wv, WHI, WLO);

  dim3 pgrid(4, 128, 3);
  proj_mfma<<<pgrid, 256, 0, stream>>>(x, WHI, WLO, KHI, KLO, VT,
                                       (unsigned short*)d_out);

  flash_mfma<<<256, 512, 0, stream>>>(KHI, KLO, VT, mask, (float*)d_out);
}